// Round 8
// baseline (256.698 us; speedup 1.0000x reference)
//
#include <hip/hip_runtime.h>

// QuaternionLinear as one 4096^3 bf16 GEMM (B^T layout).
// Round 12 (resubmit; R7 bench was an infra GPUAcquisitionTimeout, the
// kernel never ran). R11 verified (111 us qgemm, MfmaUtil 54%). The ~125
// us non-qgemm residual (prep 144 MB + overhead, stable across rounds) is
// now the biggest target. This round FUSES the A-conversion (96 MB of
// prep) into qgemm: A is staged from x (fp32) by reg-staging {asm
// global_load_dwordx4 -> bf16 cvt -> swizzled ds_write_b128}, T14-split so
// loads age >=2 phases before their vmcnt. prep shrinks to w-expansion
// only (48 MB, ~10 us). Also fixes R11's mid-tile vmcnt(4) which waited on
// 2-phase-old A-DMA (now waits only on ~6-phase-old B(t+1)).
// Register budget: acc 128 + frags. R11's 5 A-frag sets -> strict 2-set
// ping-pong (pair read exactly 1 phase ahead, -48 VGPR) pays for the +16
// staging VGPR (g0/g1 reuse the same 4 float4 regs).
// Per tile t (A buf a=t%3, B buf b=t&1), phases p0..p3 = acc-row pairs:
//  p0: load g0=A(t+2) half0 (4x dwordx4); ds: s(B ks1)+XB(P1);
//      MFMA P0ks0(XA,c); lgkm(4); MFMA P0ks1(XA,s)
//  p1: ds: XA(P2); lgkm(4)[XB done]; MFMA P1; lgkm(0)[XA done];
//      vmcnt(4)[B(t+1) done, g0 in flight]; BARRIER(mid)
//  p2: vmcnt(0)[g0 done, queue empty]; cvt g0; 2x ds_write; load g1=A(t+2)
//      half1; issue B(t+2) DMA -> Bs[b]; ds: XB(P3)+d(next ks0 from b^1);
//      MFMA P2 (XA drained @p1)
//  p3: ds: XA(next P0 from As[(t+1)%3]); lgkm(8)[XB done]; MFMA P3ks0;
//      vmcnt(4)[g1 landed, B(t+2) in flight]; cvt g1; 2x ds_write;
//      MFMA P3ks1; lgkm(0); BARRIER(end)
// vmcnt ledger (in-order queue): enter t: [B(t+1)4] -> p0 +g0: [B4,g0 4]
// -> mid vmcnt(4) drains B(t+1) -> p2 vmcnt(0) drains g0 (empty) -> +g1,
// +B(t+2): [g1 4,B4] -> p3 vmcnt(4) drains g1 -> enter t+1: [B(t+2)4]. OK
// WAR ledger: writes to As[(t+2)%3]=As[(t-1)%3] @t-p2/p3: its last readers
// (t-1 p2 xb) drained by t-1 p3 lgkm(8), published t-1 END bar < t-p2. OK
// B(t+2)->Bs[b] @t-p2: readers = s (t-p0, drained p0 lgkm(4), published
// MID bar < p2) + c (read t-1-p2 as d, published t-1 END). OK
// First readers of A(t+2): t+1-p3 XA-next; writes drained by t-p3 lgkm(0),
// published t END bar. OK. Swizzle identical to R8-R11 (0 conflicts):
// stored chunk s of row r = global chunk s^(r&7); reg-staging writes at
// position (l&7)^(l>>3). sched_barrier(0) after every wait (rule #18).

typedef __bf16 bf16x8 __attribute__((ext_vector_type(8)));
typedef float floatx4 __attribute__((ext_vector_type(4)));

constexpr int M = 4096;   // batch
constexpr int N = 4096;   // out_f * 4
constexpr int K = 4096;   // in_f * 4
constexpr int BM = 256, BN = 256, BK = 64;

constexpr int EXP_BLOCKS = (1024 * 1024 / 2) / 256;  // 2048: w -> signed Wbig

#define BARRIER() asm volatile("s_barrier" ::: "memory")
#define SB()      __builtin_amdgcn_sched_barrier(0)
#define LGKM0()   do { asm volatile("s_waitcnt lgkmcnt(0)"); SB(); } while (0)
#define LGKM4()   do { asm volatile("s_waitcnt lgkmcnt(4)"); SB(); } while (0)
#define LGKM8()   do { asm volatile("s_waitcnt lgkmcnt(8)"); SB(); } while (0)
#define VM(n)     do { asm volatile("s_waitcnt vmcnt(" #n ")"); SB(); } while (0)
#define LDS_OFF(p) ((unsigned)(uintptr_t)(__attribute__((address_space(3))) const void*)(p))

// ---------- slim prep: w -> Wbig (sign-expanded bf16), 48 MB traffic ----------
// Wbig rows (c order) per quaternion w=(r,i,j,k):
//   d=0: [+r,-i,-j,-k]  d=1: [+i,+r,+k,-j]  d=2: [+j,-k,+r,+i]  d=3: [+k,+j,-i,+r]
__global__ void prep_kernel(const float* __restrict__ w, __bf16* __restrict__ Wb) {
    const int idx = blockIdx.x * 256 + threadIdx.x;   // quaternion PAIR index
    const int o  = idx >> 9;
    const int ip = (idx & 511) * 2;
    float4 q0 = ((const float4*)w)[o * 1024 + ip];
    float4 q1 = ((const float4*)w)[o * 1024 + ip + 1];
    __bf16* base = Wb + (size_t)(o * 4) * K + ip * 4;
    bf16x8 r;
    r[0] = (__bf16)q0.x; r[1] = (__bf16)(-q0.y); r[2] = (__bf16)(-q0.z); r[3] = (__bf16)(-q0.w);
    r[4] = (__bf16)q1.x; r[5] = (__bf16)(-q1.y); r[6] = (__bf16)(-q1.z); r[7] = (__bf16)(-q1.w);
    *(bf16x8*)(base) = r;
    r[0] = (__bf16)q0.y; r[1] = (__bf16)q0.x; r[2] = (__bf16)q0.w; r[3] = (__bf16)(-q0.z);
    r[4] = (__bf16)q1.y; r[5] = (__bf16)q1.x; r[6] = (__bf16)q1.w; r[7] = (__bf16)(-q1.z);
    *(bf16x8*)(base + (size_t)K) = r;
    r[0] = (__bf16)q0.z; r[1] = (__bf16)(-q0.w); r[2] = (__bf16)q0.x; r[3] = (__bf16)q0.y;
    r[4] = (__bf16)q1.z; r[5] = (__bf16)(-q1.w); r[6] = (__bf16)q1.x; r[7] = (__bf16)q1.y;
    *(bf16x8*)(base + (size_t)2 * K) = r;
    r[0] = (__bf16)q0.w; r[1] = (__bf16)q0.z; r[2] = (__bf16)(-q0.y); r[3] = (__bf16)q0.x;
    r[4] = (__bf16)q1.w; r[5] = (__bf16)q1.z; r[6] = (__bf16)(-q1.y); r[7] = (__bf16)q1.x;
    *(bf16x8*)(base + (size_t)3 * K) = r;
}

// ---------- async global->LDS, 16B per lane (B path) ----------
__device__ __forceinline__ void gload_lds16(const __bf16* g, __bf16* l) {
    __builtin_amdgcn_global_load_lds(
        (const __attribute__((address_space(1))) void*)g,
        (__attribute__((address_space(3))) void*)l, 16, 0, 0);
}

// ---------- manual VMEM/DS ops (invisible to SIInsertWaitcnts) ----------
__device__ __forceinline__ float4 gl4(const float* p) {
    float4 r;
    asm volatile("global_load_dwordx4 %0, %1, off" : "=v"(r) : "v"(p));
    return r;
}
template <int OFF>
__device__ __forceinline__ bf16x8 dsrO(unsigned base) {
    bf16x8 r;
    asm volatile("ds_read_b128 %0, %1 offset:%c2" : "=v"(r) : "v"(base), "i"(OFF));
    return r;
}
template <int OFF>
__device__ __forceinline__ void dswO(unsigned base, bf16x8 v) {
    asm volatile("ds_write_b128 %0, %1 offset:%c2" :: "v"(base), "v"(v), "i"(OFF));
}
__device__ __forceinline__ bf16x8 cvt8(float4 a, float4 b) {
    bf16x8 v;
    v[0] = (__bf16)a.x; v[1] = (__bf16)a.y; v[2] = (__bf16)a.z; v[3] = (__bf16)a.w;
    v[4] = (__bf16)b.x; v[5] = (__bf16)b.y; v[6] = (__bf16)b.z; v[7] = (__bf16)b.w;
    return v;
}

// ---------- GEMM: C[M][N] = bf16(X[M][K]) * B[N][K]^T + bias[N] ----------
__global__ __launch_bounds__(512, 2) void qgemm_kernel(const float* __restrict__ X,
                                                       const __bf16* __restrict__ B,
                                                       const float* __restrict__ bias,
                                                       float* __restrict__ C) {
    __shared__ __bf16 As[3][BM][BK];   // 3 x 32 KiB (triple-buffered A)
    __shared__ __bf16 Bs[2][BN][BK];   // 2 x 32 KiB -> 160 KiB, 1 block/CU

    const int tid  = threadIdx.x;
    const int wave = tid >> 6;          // 0..7
    const int lane = tid & 63;

    // Bijective XCD remap: 16x16 tile grid; each XCD owns an 8Mx4N region.
    const int bid = blockIdx.x;
    const int xcd = bid & 7;
    const int q   = bid >> 3;                       // 0..31
    const int tm  = (xcd >> 2) * 8 + (q & 7);       // 0..15
    const int tn  = (xcd & 3) * 4 + (q >> 3);       // 0..15
    const int bm  = tm * BM;
    const int bn  = tn * BN;

    const int wm = (wave >> 2) * 128;   // wave_m in {0,1} -> 128-row half
    const int wn = (wave & 3) * 64;     // wave_n in 0..3  -> 64-col slice

    // ---- staging addressing ----
    // A (reg-staged from fp32 x): lane covers row stripe (l>>3), chunk l&7.
    const float* agX = X + (size_t)(bm + wave * 16 + (lane >> 3)) * 4096 + (lane & 7) * 8;
    // B (DMA): pre-swizzled source, linear LDS dest (unchanged from R8-R11).
    const int srow = wave * 16 + (lane >> 3);
    const int schk = ((lane & 7) ^ (lane >> 3)) * 8;
    const __bf16* agB = B + (size_t)(bn + srow) * K + schk;

    auto issueB = [&](int buf, int h, int t) {
        const __bf16* g = agB + (size_t)h * 128 * K + t * BK;
        gload_lds16(g,                 &Bs[buf][h * 128 + wave * 16][0]);
        gload_lds16(g + (size_t)8 * K, &Bs[buf][h * 128 + wave * 16 + 8][0]);
    };

    // A LDS write bases (swizzled dest): row = wave*16+(l>>3), chunk (l&7)^(l>>3)
    const unsigned aW0 = LDS_OFF(&As[0][0][0]) + (unsigned)((wave * 16 + (lane >> 3)) * 128)
                       + (unsigned)(((lane & 7) ^ (lane >> 3)) * 16);
    const unsigned aW1 = aW0 + 32768u, aW2 = aW0 + 65536u;
    // write offsets: +16384 = half1 (128 rows), +1024 = +8 rows

    // ---- fragment read addressing ----
    const int fl  = lane & 15;
    const int fq  = lane >> 4;
    const int fx7 = fl & 7;
    const unsigned ebo0 = (unsigned)(((fq)     ^ fx7) * 16);
    const unsigned ebo1 = (unsigned)(((4 + fq) ^ fx7) * 16);
    const unsigned aR0  = LDS_OFF(&As[0][0][0]) + (unsigned)(wm + fl) * 128u + ebo0;
    const unsigned aR1  = LDS_OFF(&As[0][0][0]) + (unsigned)(wm + fl) * 128u + ebo1;
    const unsigned aR0b1 = aR0 + 32768u, aR1b1 = aR1 + 32768u;
    const unsigned aR0b2 = aR0 + 65536u, aR1b2 = aR1 + 65536u;
    const unsigned bR0  = LDS_OFF(&Bs[0][0][0]) + (unsigned)(wn + fl) * 128u + ebo0;
    const unsigned bR1  = LDS_OFF(&Bs[0][0][0]) + (unsigned)(wn + fl) * 128u + ebo1;
    const unsigned bR0b1 = bR0 + 32768u, bR1b1 = bR1 + 32768u;

    floatx4 acc[8][4] = {};
    bf16x8 xa0, xa1, xa2, xa3;   // A ping set (frag ks0/ks1 x 2 m-frags)
    bf16x8 xb0, xb1, xb2, xb3;   // A pong set
    bf16x8 s0, s1, s2, s3;       // B ks1 (re-read each tile)
    bf16x8 bE0, bE1, bE2, bE3;   // B ks0 parity bank E
    bf16x8 bO0, bO1, bO2, bO3;   // B ks0 parity bank O
    float4 fa0, fa1, fa2, fa3;   // staging regs (g0/g1 reuse)

#define HALFK(i0, i1, AA, AB, F0, F1, F2, F3)                                     \
    acc[i0][0] = __builtin_amdgcn_mfma_f32_16x16x32_bf16(AA, F0, acc[i0][0], 0, 0, 0); \
    acc[i1][0] = __builtin_amdgcn_mfma_f32_16x16x32_bf16(AB, F0, acc[i1][0], 0, 0, 0); \
    acc[i0][1] = __builtin_amdgcn_mfma_f32_16x16x32_bf16(AA, F1, acc[i0][1], 0, 0, 0); \
    acc[i1][1] = __builtin_amdgcn_mfma_f32_16x16x32_bf16(AB, F1, acc[i1][1], 0, 0, 0); \
    acc[i0][2] = __builtin_amdgcn_mfma_f32_16x16x32_bf16(AA, F2, acc[i0][2], 0, 0, 0); \
    acc[i1][2] = __builtin_amdgcn_mfma_f32_16x16x32_bf16(AB, F2, acc[i1][2], 0, 0, 0); \
    acc[i0][3] = __builtin_amdgcn_mfma_f32_16x16x32_bf16(AA, F3, acc[i0][3], 0, 0, 0); \
    acc[i1][3] = __builtin_amdgcn_mfma_f32_16x16x32_bf16(AB, F3, acc[i1][3], 0, 0, 0)

    // A0c/A1c: cur A buf bases (ks0/ks1); A0n/A1n: next A buf; B0c/B1c: cur
    // B; B0x: other-parity B ks0; AW: write base for As[(t+2)%3]; BC*/BX*:
    // cur/next B-ks0 reg banks; DB: Bs buf for B(t+2).
#define TILE(T, A0c, A1c, A0n, A1n, B0c, B1c, B0x, AW, BC0, BC1, BC2, BC3,        \
             BX0, BX1, BX2, BX3, DB, ISSA, ISSB, MIDVM)                           \
    do {                                                                          \
        /* p0 */                                                                  \
        if (ISSA) {                                                               \
            const float* g_ = agX + (size_t)((T) + 2) * 64;                       \
            fa0 = gl4(g_);          fa1 = gl4(g_ + 4);                            \
            fa2 = gl4(g_ + 32768);  fa3 = gl4(g_ + 32772);                        \
        }                                                                         \
        s0 = dsrO<0>(B1c); s1 = dsrO<2048>(B1c);                                  \
        s2 = dsrO<4096>(B1c); s3 = dsrO<6144>(B1c);                               \
        xb0 = dsrO<4096>(A0c); xb1 = dsrO<4096>(A1c);                             \
        xb2 = dsrO<6144>(A0c); xb3 = dsrO<6144>(A1c);                             \
        SB();                                                                     \
        __builtin_amdgcn_s_setprio(1);                                            \
        HALFK(0, 1, xa0, xa2, BC0, BC1, BC2, BC3);                                \
        __builtin_amdgcn_s_setprio(0);                                            \
        LGKM4();                                                                  \
        __builtin_amdgcn_s_setprio(1);                                            \
        HALFK(0, 1, xa1, xa3, s0, s1, s2, s3);                                    \
        __builtin_amdgcn_s_setprio(0);                                            \
        /* p1 */                                                                  \
        xa0 = dsrO<8192>(A0c); xa1 = dsrO<8192>(A1c);                             \
        xa2 = dsrO<10240>(A0c); xa3 = dsrO<10240>(A1c);                           \
        SB();                                                                     \
        LGKM4();                                                                  \
        __builtin_amdgcn_s_setprio(1);                                            \
        HALFK(2, 3, xb0, xb2, BC0, BC1, BC2, BC3);                                \
        HALFK(2, 3, xb1, xb3, s0, s1, s2, s3);                                    \
        __builtin_amdgcn_s_setprio(0);                                            \
        LGKM0();                                                                  \
        asm volatile("s_waitcnt vmcnt(" #MIDVM ")");                              \
        BARRIER();                                                                \
        /* p2 */                                                                  \
        if (ISSA) {                                                               \
            VM(0);  /* g0 landed (queue was [g0] only) */                         \
            dswO<0>(AW, cvt8(fa0, fa1));                                          \
            dswO<1024>(AW, cvt8(fa2, fa3));                                       \
            const float* g_ = agX + (size_t)((T) + 2) * 64 + 524288;              \
            fa0 = gl4(g_);          fa1 = gl4(g_ + 4);                            \
            fa2 = gl4(g_ + 32768);  fa3 = gl4(g_ + 32772);                        \
        }                                                                         \
        if (ISSB) { issueB(DB, 0, (T) + 2); issueB(DB, 1, (T) + 2); }             \
        xb0 = dsrO<12288>(A0c); xb1 = dsrO<12288>(A1c);                           \
        xb2 = dsrO<14336>(A0c); xb3 = dsrO<14336>(A1c);                           \
        BX0 = dsrO<0>(B0x); BX1 = dsrO<2048>(B0x);                                \
        BX2 = dsrO<4096>(B0x); BX3 = dsrO<6144>(B0x);                             \
        SB();                                                                     \
        __builtin_amdgcn_s_setprio(1);                                            \
        HALFK(4, 5, xa0, xa2, BC0, BC1, BC2, BC3);                                \
        HALFK(4, 5, xa1, xa3, s0, s1, s2, s3);                                    \
        __builtin_amdgcn_s_setprio(0);                                            \
        /* p3 */                                                                  \
        xa0 = dsrO<0>(A0n); xa1 = dsrO<0>(A1n);                                   \
        xa2 = dsrO<2048>(A0n); xa3 = dsrO<2048>(A1n);                             \
        SB();                                                                     \
        LGKM8();  /* xb (+g0 writes) drained */                                   \
        __builtin_amdgcn_s_setprio(1);                                            \
        HALFK(6, 7, xb0, xb2, BC0, BC1, BC2, BC3);                                \
        __builtin_amdgcn_s_setprio(0);                                            \
        if (ISSA) {                                                               \
            VM(4);  /* g1 landed; B(t+2) stays in flight */                       \
            dswO<16384>(AW, cvt8(fa0, fa1));                                      \
            dswO<17408>(AW, cvt8(fa2, fa3));                                      \
        }                                                                         \
        __builtin_amdgcn_s_setprio(1);                                            \
        HALFK(6, 7, xb1, xb3, s0, s1, s2, s3);                                    \
        __builtin_amdgcn_s_setprio(0);                                            \
        LGKM0();                                                                  \
        BARRIER();                                                                \
    } while (0)

    // ---- prologue: A(0),A(1) via reg-staging; B(0),B(1) DMA ----
    {
        const float* g_ = agX;               // A(0) half0
        fa0 = gl4(g_); fa1 = gl4(g_ + 4); fa2 = gl4(g_ + 32768); fa3 = gl4(g_ + 32772);
        VM(0);
        dswO<0>(aW0, cvt8(fa0, fa1)); dswO<1024>(aW0, cvt8(fa2, fa3));
        g_ = agX + 524288;                   // A(0) half1
        fa0 = gl4(g_); fa1 = gl4(g_ + 4); fa2 = gl4(g_ + 32768); fa3 = gl4(g_ + 32772);
        VM(0);
        dswO<16384>(aW0, cvt8(fa0, fa1)); dswO<17408>(aW0, cvt8(fa2, fa3));
        g_ = agX + 64;                       // A(1) half0
        fa0 = gl4(g_); fa1 = gl4(g_ + 4); fa2 = gl4(g_ + 32768); fa3 = gl4(g_ + 32772);
        VM(0);
        dswO<0>(aW1, cvt8(fa0, fa1)); dswO<1024>(aW1, cvt8(fa2, fa3));
        g_ = agX + 64 + 524288;              // A(1) half1
        fa0 = gl4(g_); fa1 = gl4(g_ + 4); fa2 = gl4(g_ + 32768); fa3 = gl4(g_ + 32772);
        VM(0);
        dswO<16384>(aW1, cvt8(fa0, fa1)); dswO<17408>(aW1, cvt8(fa2, fa3));
    }
    issueB(0, 0, 0); issueB(0, 1, 0);
    issueB(1, 0, 1); issueB(1, 1, 1);
    VM(4);                                   // B(0) landed; B(1) in flight
    LGKM0();                                 // A writes drained
    BARRIER();
    xa0 = dsrO<0>(aR0);    xa1 = dsrO<0>(aR1);
    xa2 = dsrO<2048>(aR0); xa3 = dsrO<2048>(aR1);
    bE0 = dsrO<0>(bR0);    bE1 = dsrO<2048>(bR0);
    bE2 = dsrO<4096>(bR0); bE3 = dsrO<6144>(bR0);
    LGKM0();

    for (int t = 0; t < 60; t += 6) {
        TILE(t + 0, aR0,   aR1,   aR0b1, aR1b1, bR0,   bR1,   bR0b1, aW2,
             bE0, bE1, bE2, bE3, bO0, bO1, bO2, bO3, 0, true, true, 4);
        TILE(t + 1, aR0b1, aR1b1, aR0b2, aR1b2, bR0b1, bR1b1, bR0,   aW0,
             bO0, bO1, bO2, bO3, bE0, bE1, bE2, bE3, 1, true, true, 4);
        TILE(t + 2, aR0b2, aR1b2, aR0,   aR1,   bR0,   bR1,   bR0b1, aW1,
             bE0, bE1, bE2, bE3, bO0, bO1, bO2, bO3, 0, true, true, 4);
        TILE(t + 3, aR0,   aR1,   aR0b1, aR1b1, bR0b1, bR1b1, bR0,   aW2,
             bO0, bO1, bO2, bO3, bE0, bE1, bE2, bE3, 1, true, true, 4);
        TILE(t + 4, aR0b1, aR1b1, aR0b2, aR1b2, bR0,   bR1,   bR0b1, aW0,
             bE0, bE1, bE2, bE3, bO0, bO1, bO2, bO3, 0, true, true, 4);
        TILE(t + 5, aR0b2, aR1b2, aR0,   aR1,   bR0b1, bR1b1, bR0,   aW1,
             bO0, bO1, bO2, bO3, bE0, bE1, bE2, bE3, 1, true, true, 4);
    }
    TILE(60, aR0,   aR1,   aR0b1, aR1b1, bR0,   bR1,   bR0b1, aW2,
         bE0, bE1, bE2, bE3, bO0, bO1, bO2, bO3, 0, true,  true,  4);
    TILE(61, aR0b1, aR1b1, aR0b2, aR1b2, bR0b1, bR1b1, bR0,   aW0,
         bO0, bO1, bO2, bO3, bE0, bE1, bE2, bE3, 1, true,  true,  4);
    TILE(62, aR0b2, aR1b2, aR0,   aR1,   bR0,   bR1,   bR0b1, aW1,
         bE0, bE1, bE2, bE3, bO0, bO1, bO2, bO3, 0, false, false, 0);

    // ---- peeled tile 63 (A buf 0, B buf 1, c = bO): reads + MFMA only ----
    {
        s0 = dsrO<0>(bR1b1); s1 = dsrO<2048>(bR1b1);
        s2 = dsrO<4096>(bR1b1); s3 = dsrO<6144>(bR1b1);
        xb0 = dsrO<4096>(aR0); xb1 = dsrO<4096>(aR1);
        xb2 = dsrO<6144>(aR0); xb3 = dsrO<6144>(aR1);
        SB();
        __builtin_amdgcn_s_setprio(1);
        HALFK(0, 1, xa0, xa2, bO0, bO1, bO2, bO3);
        __builtin_amdgcn_s_setprio(0);
        LGKM4();
        __builtin_amdgcn_s_setprio(1);
        HALFK(0, 1, xa1, xa3, s0, s1, s2, s3);
        __builtin_amdgcn_s_setprio(0);
        xa0 = dsrO<8192>(aR0); xa1 = dsrO<8192>(aR1);
        xa2 = dsrO<10240>(aR0); xa3 = dsrO<10240>(aR1);
        SB();
        LGKM4();
        __builtin_amdgcn_s_setprio(1);
        HALFK(2, 3, xb0, xb2, bO0, bO1, bO2, bO3);
        HALFK(2, 3, xb1, xb3, s0, s1, s2, s3);
        __builtin_amdgcn_s_setprio(0);
        LGKM0();
        xb0 = dsrO<12288>(aR0); xb1 = dsrO<12288>(aR1);
        xb2 = dsrO<14336>(aR0); xb3 = dsrO<14336>(aR1);
        SB();
        __builtin_amdgcn_s_setprio(1);
        HALFK(4, 5, xa0, xa2, bO0, bO1, bO2, bO3);
        HALFK(4, 5, xa1, xa3, s0, s1, s2, s3);
        __builtin_amdgcn_s_setprio(0);
        LGKM0();
        __builtin_amdgcn_s_setprio(1);
        HALFK(6, 7, xb0, xb2, bO0, bO1, bO2, bO3);
        HALFK(6, 7, xb1, xb3, s0, s1, s2, s3);
        __builtin_amdgcn_s_setprio(0);
    }

    // epilogue: C/D layout col = lane&15, row = (lane>>4)*4 + reg (verified R1)
#pragma unroll
    for (int mt = 0; mt < 8; ++mt) {
        const int row = bm + wm + mt * 16 + fq * 4;
#pragma unroll
        for (int nt = 0; nt < 4; ++nt) {
            const int col = bn + wn + nt * 16 + fl;
            const float bv = bias[col];
            float* cp = C + (size_t)row * N + col;
#pragma unroll
            for (int r = 0; r < 4; ++r)
                cp[(size_t)r * N] = acc[mt][nt][r] + bv;
        }
    }
#undef TILE
#undef HALFK
}

extern "C" void kernel_launch(void* const* d_in, const int* in_sizes, int n_in,
                              void* d_out, int out_size, void* d_ws, size_t ws_size,
                              hipStream_t stream) {
    const float* x    = (const float*)d_in[0];   // (4096,1024,4) fp32
    const float* w    = (const float*)d_in[1];   // (1024,1024,4) fp32
    const float* bias = (const float*)d_in[2];   // (1024,4) fp32
    float* out = (float*)d_out;                  // (4096,1024,4) fp32

    __bf16* Wbig = (__bf16*)d_ws;                // 32 MB

    prep_kernel<<<EXP_BLOCKS, 256, 0, stream>>>(w, Wbig);

    qgemm_kernel<<<256, 512, 0, stream>>>(x, Wbig, bias, out);
}